// Round 9
// baseline (12732.598 us; speedup 1.0000x reference)
//
#include <hip/hip_runtime.h>
#include <math.h>

#define T_LEN 4096
#define EDIM  256
#define HDIM  512
#define NTAGS 50
#define SENTW 0xFFFFFFFFu

__device__ __forceinline__ float sigm(float x) {
    return __builtin_amdgcn_rcpf(1.0f + __expf(-x));
}
__device__ __forceinline__ float tanh_fast(float x) {
    float e = __expf(2.0f * x);                       // x>>0 -> inf -> rcp=0 -> 1; x<<0 -> 0 -> -1
    return 1.0f - 2.0f * __builtin_amdgcn_rcpf(e + 1.0f);
}
__device__ __forceinline__ float u2f(unsigned u) { union { unsigned i; float f; } v; v.i = u; return v.f; }
// Agent-scope relaxed atomic load: serviced at the device coherence point.
// Laws from rounds 0-8: only coherence-point ops observe cross-CU progress;
// L2-shortcut protocols never work (r1/r2/r5); ring mailboxes don't reduce
// poll RT (r7); same-line poll pipelining MSHR-merges (r3); never sample a
// flag before the program-order publish that may cover it (r8).
__device__ __forceinline__ unsigned long long pollA(const unsigned long long* p) {
    return __hip_atomic_load(p, __ATOMIC_RELAXED, __HIP_MEMORY_SCOPE_AGENT);
}
__device__ __forceinline__ bool bad2(unsigned long long v) {
    return ((unsigned)v == SENTW) || ((unsigned)(v >> 32) == SENTW);
}

// ---------------------------------------------------------------------------
// Persistent bidirectional LSTM scan (f32). Round-9: BARRIER-FREE FULL-ROW
// WAVES + LDS-broadcast matvec. Sync semantics byte-equivalent to r4 (proven
// 5.94 ms): pure agent ops, tight spin, publish-then-poll ordering.
//
// Why: with 1 block/CU, waves have no co-resident partner; every instruction
// costs ~2cy serialized. r4 spent 192 FMA + 192 v_readlane (~768cy) plus
// barrier + LDS reduce + wave0-serial finalize (~350cy) per step. This
// version removes ALL intra-block coupling and halves broadcast overhead:
//   * Wave w of block g owns units gg*16+w*4+{0..3} = 16 full gate rows
//     (4 gates x 4 units, all 512 h-cols). No cross-wave reduction =>
//     no __syncthreads, no pl[] handoff, no wave0 tail. Publish happens
//     right after an in-wave 2x shfl_xor reduce + 4-lane finalize.
//   * Lane = r*4+c (r=row 0..15, c=colblock 0..3) holds W_hh[R][c*128+i]
//     (128 regs) and W_ih[R][c*64+i] (64). h/x broadcast via per-wave LDS
//     strips: lane polls the 4x8B words holding h[8*lane..+7], writes them
//     to the strip; matvec = 32x (ds_read_b128, 16-lane same-addr broadcast,
//     conflict-free by 132/68-float c-stride) + 4 FMAs. Instruction count
//     per step ~300 vs r4's ~430.
// ---------------------------------------------------------------------------
__global__ __launch_bounds__(256, 1) void lstm_scan(
    const int* __restrict__ sent, const float* __restrict__ emb,
    const float* __restrict__ Wih_f, const float* __restrict__ Whh_f,
    const float* __restrict__ bih_f, const float* __restrict__ bhh_f,
    const float* __restrict__ Wih_b, const float* __restrict__ Whh_b,
    const float* __restrict__ bih_b, const float* __restrict__ bhh_b,
    float* hsf, float* hsb)
{
    const int tid  = threadIdx.x;
    const int lane = tid & 63;
    const int w    = tid >> 6;          // wave id
    const int dir  = blockIdx.x >> 5;
    const int g    = blockIdx.x & 31;

    const float* Wih = dir ? Wih_b : Wih_f;
    const float* Whh = dir ? Whh_b : Whh_f;
    const float* bih = dir ? bih_b : bih_f;
    const float* bhh = dir ? bhh_b : bhh_f;
    float* hs = dir ? hsb : hsf;

    const int r = lane >> 2;            // row-in-wave 0..15
    const int c = lane & 3;             // colblock 0..3
    const int q = r >> 2;               // gate (i,f,g,o)
    const int m = r & 3;                // unit-in-wave
    const int R = q * 512 + g * 16 + w * 4 + m;   // gate row in [0,2048)

    // W_hh[R][c*128 + i] -> 128 VGPRs (or compiler-sunk L1 reloads - benign,
    // poll-independent, proven r4/r6).
    float wh[128];
    {
        const float* base = Whh + (size_t)R * HDIM + c * 128;
        #pragma unroll
        for (int i = 0; i < 32; ++i) {
            float4 v = *(const float4*)(base + 4 * i);
            wh[4*i] = v.x; wh[4*i+1] = v.y; wh[4*i+2] = v.z; wh[4*i+3] = v.w;
        }
    }
    // W_ih[R][c*64 + i] -> 64 VGPRs.
    float wx[64];
    {
        const float* base = Wih + (size_t)R * EDIM + c * 64;
        #pragma unroll
        for (int i = 0; i < 16; ++i) {
            float4 v = *(const float4*)(base + 4 * i);
            wx[4*i] = v.x; wx[4*i+1] = v.y; wx[4*i+2] = v.z; wx[4*i+3] = v.w;
        }
    }
    // Finalize biases: lanes 0..3 own unit uu = g*16 + w*4 + lane.
    float bi = 0.f, bff = 0.f, bgg = 0.f, boo = 0.f;
    if (lane < 4) {
        int uu = g * 16 + w * 4 + lane;
        bi  = bih[uu]        + bhh[uu];
        bff = bih[512 + uu]  + bhh[512 + uu];
        bgg = bih[1024 + uu] + bhh[1024 + uu];
        boo = bih[1536 + uu] + bhh[1536 + uu];
    }

    // Per-wave private LDS strips (intra-wave producer/consumer only -> no
    // barriers; waitcnt orders same-wave LDS ops). c-stride 132/68 staggers
    // banks so the 4 distinct c-addresses of each broadcast read never alias.
    __shared__ float hls[4][528];       // [wave][c*132 + pos], pos<128
    __shared__ float xls[4][2][272];    // [wave][step parity][c*68 + pos]

    float c_state = 0.0f;               // lanes 0..3

    const int cp = lane >> 4;           // write-side strip block (owns 8/4 vals)
    const int pw = lane & 15;

    // Preload x[first t]: lane holds emb[sent[t0]][4*lane..+3].
    float4 ecur;
    {
        int t0 = dir ? (T_LEN - 1) : 0;
        ecur = *(const float4*)(emb + (size_t)sent[t0] * EDIM + 4 * lane);
    }
    *(float4*)&xls[w][0][cp * 68 + pw * 4] = ecur;

    for (int s = 0; s < T_LEN; ++s) {
        const int t  = dir ? (T_LEN - 1 - s) : s;
        const int sb = s & 1;

        // Issue poll samples ASAP (4x8B words = h[8*lane..+7] of step s-1);
        // they fly under the x-matvec. Issued strictly AFTER our own publish
        // of step s-1 (program order) - r8 lesson.
        const unsigned long long* p = nullptr;
        unsigned long long v0 = 0, v1 = 0, v2 = 0, v3 = 0;
        if (s > 0) {
            const int tp = dir ? (t + 1) : (t - 1);
            p = (const unsigned long long*)(hs + (size_t)tp * HDIM) + 4 * lane;
            v0 = pollA(p); v1 = pollA(p + 1); v2 = pollA(p + 2); v3 = pollA(p + 3);
        }
        // Prefetch next step's embedding segment (h-independent).
        float4 enext = make_float4(0.f, 0.f, 0.f, 0.f);
        if (s + 1 < T_LEN) {
            int tn = dir ? (t - 1) : (t + 1);
            enext = *(const float4*)(emb + (size_t)sent[tn] * EDIM + 4 * lane);
        }

        // x partial: 16 broadcast ds_read_b128 + 64 FMAs (under poll RT).
        float a0 = 0.f, a1 = 0.f, a2 = 0.f, a3 = 0.f;
        #pragma unroll
        for (int i = 0; i < 16; ++i) {
            float4 xv = *(const float4*)&xls[w][sb][c * 68 + 4 * i];
            a0 = fmaf(wx[4*i+0], xv.x, a0);
            a1 = fmaf(wx[4*i+1], xv.y, a1);
            a2 = fmaf(wx[4*i+2], xv.z, a2);
            a3 = fmaf(wx[4*i+3], xv.w, a3);
        }

        if (s > 0) {
            // Tight spin: reload all 4 words (independent addrs -> parallel
            // RT, one wait). Wave converges when every lane's 8 values good.
            while (bad2(v0) | bad2(v1) | bad2(v2) | bad2(v3)) {
                v0 = pollA(p); v1 = pollA(p + 1); v2 = pollA(p + 2); v3 = pollA(p + 3);
            }
            // Stage h into this wave's strip; also stage next x (batched, one
            // implicit lgkmcnt before the reads below).
            float4 ha = make_float4(u2f((unsigned)v0), u2f((unsigned)(v0 >> 32)),
                                    u2f((unsigned)v1), u2f((unsigned)(v1 >> 32)));
            float4 hb = make_float4(u2f((unsigned)v2), u2f((unsigned)(v2 >> 32)),
                                    u2f((unsigned)v3), u2f((unsigned)(v3 >> 32)));
            *(float4*)&hls[w][cp * 132 + pw * 8]     = ha;
            *(float4*)&hls[w][cp * 132 + pw * 8 + 4] = hb;
            if (s + 1 < T_LEN)
                *(float4*)&xls[w][sb ^ 1][cp * 68 + pw * 4] = enext;

            // h partial: 32 broadcast ds_read_b128 + 128 FMAs.
            #pragma unroll
            for (int i = 0; i < 32; ++i) {
                float4 hv = *(const float4*)&hls[w][c * 132 + 4 * i];
                a0 = fmaf(wh[4*i+0], hv.x, a0);
                a1 = fmaf(wh[4*i+1], hv.y, a1);
                a2 = fmaf(wh[4*i+2], hv.z, a2);
                a3 = fmaf(wh[4*i+3], hv.w, a3);
            }
        } else {
            if (s + 1 < T_LEN)
                *(float4*)&xls[w][sb ^ 1][cp * 68 + pw * 4] = enext;
        }

        // In-wave reduce over colblocks (lanes r*4+{0..3}).
        float val = (a0 + a1) + (a2 + a3);
        val += __shfl_xor(val, 1, 64);
        val += __shfl_xor(val, 2, 64);
        // Gather i,f,g,o for unit mm onto lane mm (rows q*4+mm -> lanes 16q+4mm).
        const int mm = lane & 3;
        float gi = __shfl(val,      4 * mm, 64);
        float gf = __shfl(val, 16 + 4 * mm, 64);
        float gG = __shfl(val, 32 + 4 * mm, 64);
        float go = __shfl(val, 48 + 4 * mm, 64);
        if (lane < 4) {
            float iv = sigm(gi + bi), fv = sigm(gf + bff);
            float gv = tanh_fast(gG + bgg), ov = sigm(go + boo);
            c_state = fv * c_state + iv * gv;
            float h = ov * tanh_fast(c_state);
            // Publish at the coherence point (flag + archive in one store).
            __hip_atomic_exchange(hs + (size_t)t * HDIM + g * 16 + w * 4 + lane, h,
                                  __ATOMIC_RELAXED, __HIP_MEMORY_SCOPE_AGENT);
        }
    }
}

// ---------------------------------------------------------------------------
// tag_space[t] = [hs_f[t] | hs_b[t]] @ W_out^T + b_out  (f32 out)
// ---------------------------------------------------------------------------
__global__ __launch_bounds__(256) void out_gemm(
    const float* __restrict__ hsf, const float* __restrict__ hsb,
    const float* __restrict__ Wout, const float* __restrict__ bout,
    float* __restrict__ out)
{
    const int t   = blockIdx.x;
    const int tid = threadIdx.x;
    __shared__ float h2[1024];

    if (tid < 128)
        *(float4*)(h2 + tid * 4) = *(const float4*)(hsf + (size_t)t * HDIM + tid * 4);
    else
        *(float4*)(h2 + 512 + (tid - 128) * 4) = *(const float4*)(hsb + (size_t)t * HDIM + (tid - 128) * 4);
    __syncthreads();

    const int wv = tid >> 6, lane = tid & 63;
    for (int tag = wv; tag < NTAGS; tag += 4) {
        const float4* wr = (const float4*)(Wout + (size_t)tag * (2 * HDIM));
        float p = 0.0f;
        #pragma unroll
        for (int c = lane; c < 256; c += 64) {
            float4 wv4 = wr[c];
            float4 hv  = *(const float4*)(h2 + c * 4);
            p += wv4.x * hv.x + wv4.y * hv.y + wv4.z * hv.z + wv4.w * hv.w;
        }
        p += __shfl_down(p, 32, 64);
        p += __shfl_down(p, 16, 64);
        p += __shfl_down(p, 8, 64);
        p += __shfl_down(p, 4, 64);
        p += __shfl_down(p, 2, 64);
        p += __shfl_down(p, 1, 64);
        if (lane == 0) out[(size_t)t * NTAGS + tag] = p + bout[tag];
    }
}

// ---------------------------------------------------------------------------
extern "C" void kernel_launch(void* const* d_in, const int* in_sizes, int n_in,
                              void* d_out, int out_size, void* d_ws, size_t ws_size,
                              hipStream_t stream)
{
    const int*   sent  = (const int*)d_in[0];
    const float* emb   = (const float*)d_in[1];
    const float* Wih_f = (const float*)d_in[2];
    const float* Whh_f = (const float*)d_in[3];
    const float* bih_f = (const float*)d_in[4];
    const float* bhh_f = (const float*)d_in[5];
    const float* Wih_b = (const float*)d_in[6];
    const float* Whh_b = (const float*)d_in[7];
    const float* bih_b = (const float*)d_in[8];
    const float* bhh_b = (const float*)d_in[9];
    const float* Wout  = (const float*)d_in[10];
    const float* bout  = (const float*)d_in[11];
    float* out = (float*)d_out;

    char* ws = (char*)d_ws;
    // Workspace: hsf [4096*512 f32] @ 0 (8 MiB), hsb @ 8 MiB. Both double as
    // sync flags: sentinel-fill with 0xFF (-NaN, never produced by o*tanh(c)).
    float* hsf = (float*)(ws);
    float* hsb = (float*)(ws + 8388608);
    hipMemsetAsync(ws, 0xFF, 16777216, stream);

    lstm_scan<<<64, 256, 0, stream>>>(sent, emb,
                                      Wih_f, Whh_f, bih_f, bhh_f,
                                      Wih_b, Whh_b, bih_b, bhh_b,
                                      hsf, hsb);
    out_gemm<<<T_LEN, 256, 0, stream>>>(hsf, hsb, Wout, bout, out);
}

// Round 10
// 9484.206 us; speedup vs baseline: 1.3425x; 1.3425x over previous
//
#include <hip/hip_runtime.h>
#include <math.h>

#define T_LEN 4096
#define EDIM  256
#define HDIM  512
#define NTAGS 50
#define SENTW 0xFFFFFFFFu

__device__ __forceinline__ float sigm(float x) {
    return __builtin_amdgcn_rcpf(1.0f + __expf(-x));
}
__device__ __forceinline__ float tanh_fast(float x) {
    float e = __expf(2.0f * x);                       // x>>0 -> inf -> rcp=0 -> 1; x<<0 -> 0 -> -1
    return 1.0f - 2.0f * __builtin_amdgcn_rcpf(e + 1.0f);
}
__device__ __forceinline__ float u2f(unsigned u) { union { unsigned i; float f; } v; v.i = u; return v.f; }
__device__ __forceinline__ float rdlane(float v, int l) {
    union { float f; int i; } a, r;
    a.f = v;
    r.i = __builtin_amdgcn_readlane(a.i, l);   // SGPR broadcast, VALU-only
    return r.f;
}
// Agent-scope relaxed RMW poll: serviced at the device coherence point.
// Laws from rounds 0-9: only coherence-point ops observe cross-CU progress;
// L2-shortcut protocols never work (r1/r2/r5); ring mailboxes don't cut poll
// RT (r7); same-line poll pipelining MSHR-merges (r3); tight one-word-per-
// lane spin with 8-producer convergence beats every restructure (r6/r9);
// never sample a flag before the program-order publish it may cover (r8).
__device__ __forceinline__ unsigned long long pollA(unsigned long long* p) {
    return __hip_atomic_fetch_or(p, 0ull, __ATOMIC_RELAXED, __HIP_MEMORY_SCOPE_AGENT);
}
__device__ __forceinline__ bool bad2(unsigned long long v) {
    return ((unsigned)v == SENTW) || ((unsigned)(v >> 32) == SENTW);
}

// ---------------------------------------------------------------------------
// Persistent bidirectional LSTM scan (f32), data-as-flag sync, SGPR-broadcast
// matvec. Round-10 = round-4 per-direction structure (proven 5.94 ms),
// DIRECTION-PAIRED ON THE CU:
//   * 32 blocks x 512 threads. Waves 0-3 = fwd half (r4 block g), waves 4-7
//     = bwd half (r4 block 32+g). The two recurrences are independent; with
//     2 waves/SIMD the scheduler issues one direction's matvec while the
//     other direction's waves are vmcnt-stalled in their poll spin (m114
//     co-scheduling: time ~ max, not sum). r4 left the SIMDs idle ~2/3 of
//     each step; combined issue work (~2x1080cy) fits inside the ~2300cy
//     sync-stall window.
//   * Inside each half everything is byte-identical r4: pure agent-scope
//     sync, tight single-outstanding per-lane spin (8-producer convergence
//     per wave), 4 independent FMA chains, fast activations, wave0-of-half
//     finalize, one 16-lane atomicExch publish (single 64B line at the TCC).
//   * Shared __syncthreads couples the halves' jitter (cost accepted).
// WG g, half d: owns hidden units [g*16,+16) of direction d => 64 gate rows.
// lane = row: q = lane>>4 (gate i,f,g,o), u = lane&15, R = q*512 + g*16 + u.
// Wave wv (in half) owns W_hh cols [wv*128,+128), W_ih cols [wv*64,+64);
// lane l polls the 8B word covering h cols {wv*128+2l, +1}.
// ---------------------------------------------------------------------------
__global__ __launch_bounds__(512, 1) void lstm_scan(
    const int* __restrict__ sent, const float* __restrict__ emb,
    const float* __restrict__ Wih_f, const float* __restrict__ Whh_f,
    const float* __restrict__ bih_f, const float* __restrict__ bhh_f,
    const float* __restrict__ Wih_b, const float* __restrict__ Whh_b,
    const float* __restrict__ bih_b, const float* __restrict__ bhh_b,
    float* hsf, float* hsb)
{
    const int tid  = threadIdx.x;
    const int lane = tid & 63;
    const int wv   = (tid >> 6) & 3;    // wave id within half = column block
    const int dir  = tid >> 8;          // 0 = fwd half, 1 = bwd half
    const int g    = blockIdx.x;        // 0..31

    const float* Wih = dir ? Wih_b : Wih_f;
    const float* Whh = dir ? Whh_b : Whh_f;
    const float* bih = dir ? bih_b : bih_f;
    const float* bhh = dir ? bhh_b : bhh_f;
    float* hs = dir ? hsb : hsf;

    const int q = lane >> 4;
    const int u = lane & 15;
    const int R = q * 512 + g * 16 + u;

    // W_hh cols [wv*128,+128) of row R -> 128 VGPRs.
    float wh[128];
    {
        const float* base = Whh + (size_t)R * HDIM + wv * 128;
        #pragma unroll
        for (int i = 0; i < 32; ++i) {
            float4 v = *(const float4*)(base + 4 * i);
            wh[4*i] = v.x; wh[4*i+1] = v.y; wh[4*i+2] = v.z; wh[4*i+3] = v.w;
        }
    }
    // W_ih cols [wv*64,+64) of row R -> 64 VGPRs.
    float wx[64];
    {
        const float* base = Wih + (size_t)R * EDIM + wv * 64;
        #pragma unroll
        for (int i = 0; i < 16; ++i) {
            float4 v = *(const float4*)(base + 4 * i);
            wx[4*i] = v.x; wx[4*i+1] = v.y; wx[4*i+2] = v.z; wx[4*i+3] = v.w;
        }
    }
    const float bias = bih[R] + bhh[R];

    __shared__ float pl[2][2][256];     // [half][step parity][wv*64+lane]
    float c_state = 0.0f;

    // Embedding value pipeline: lane holds emb[sent[t]][wv*64 + lane].
    float ecur;
    {
        int t0 = dir ? (T_LEN - 1) : 0;
        ecur = emb[(size_t)sent[t0] * EDIM + wv * 64 + lane];
    }

    for (int s = 0; s < T_LEN; ++s) {
        const int t = dir ? (T_LEN - 1 - s) : s;

        // Issue first poll sample ASAP so it flies under the x-matvec.
        unsigned long long* p = nullptr;
        unsigned long long v = 0;
        if (s > 0) {
            const int tp = dir ? (t + 1) : (t - 1);
            p = (unsigned long long*)(hs + (size_t)tp * HDIM + wv * 128) + lane;
            v = pollA(p);
        }
        // Prefetch next step's embedding value (h-independent).
        float enext = 0.0f;
        if (s + 1 < T_LEN) {
            int tn = dir ? (t - 1) : (t + 1);
            enext = emb[(size_t)sent[tn] * EDIM + wv * 64 + lane];
        }

        // x partial: 64 SGPR-broadcast MACs over 4 independent accumulators
        // (hidden under the in-flight first poll).
        float a0 = 0.f, a1 = 0.f, a2 = 0.f, a3 = 0.f;
        #pragma unroll
        for (int i = 0; i < 16; ++i) {
            a0 = fmaf(wx[4*i+0], rdlane(ecur, 4*i+0), a0);
            a1 = fmaf(wx[4*i+1], rdlane(ecur, 4*i+1), a1);
            a2 = fmaf(wx[4*i+2], rdlane(ecur, 4*i+2), a2);
            a3 = fmaf(wx[4*i+3], rdlane(ecur, 4*i+3), a3);
        }

        if (s > 0) {
            // Tight single-outstanding spin (r4-proven). While this wave is
            // vmcnt-stalled, the other direction's waves own the SIMD.
            while (bad2(v)) v = pollA(p);
            float h0 = u2f((unsigned)v);
            float h1 = u2f((unsigned)(v >> 32));
            // h partial: 128 SGPR-broadcast MACs, 4 chains.
            #pragma unroll
            for (int i = 0; i < 32; ++i) {
                a0 = fmaf(wh[4*i+0], rdlane(h0, 2*i+0), a0);
                a1 = fmaf(wh[4*i+1], rdlane(h1, 2*i+0), a1);
                a2 = fmaf(wh[4*i+2], rdlane(h0, 2*i+1), a2);
                a3 = fmaf(wh[4*i+3], rdlane(h1, 2*i+1), a3);
            }
        }

        pl[dir][s & 1][wv * 64 + lane] = (a0 + a1) + (a2 + a3);
        __syncthreads();

        // wave0-of-half finalize (r4 structure), fast activations, one
        // 16-lane atomicExch wave-op = single 64B-line publish at the TCC.
        if (wv == 0) {
            const float* pb = pl[dir][s & 1];
            float tot = pb[lane] + pb[64 + lane] + pb[128 + lane] + pb[192 + lane] + bias;
            float gi = __shfl(tot, u,      64);
            float gf = __shfl(tot, u + 16, 64);
            float gg = __shfl(tot, u + 32, 64);
            float go = __shfl(tot, u + 48, 64);
            if (lane < 16) {
                float iv = sigm(gi), fv = sigm(gf);
                float gv = tanh_fast(gg), ov = sigm(go);
                c_state = fv * c_state + iv * gv;
                float h = ov * tanh_fast(c_state);
                __hip_atomic_exchange(hs + (size_t)t * HDIM + g * 16 + u, h,
                                      __ATOMIC_RELAXED, __HIP_MEMORY_SCOPE_AGENT);
            }
        }
        ecur = enext;
    }
}

// ---------------------------------------------------------------------------
// tag_space[t] = [hs_f[t] | hs_b[t]] @ W_out^T + b_out  (f32 out)
// ---------------------------------------------------------------------------
__global__ __launch_bounds__(256) void out_gemm(
    const float* __restrict__ hsf, const float* __restrict__ hsb,
    const float* __restrict__ Wout, const float* __restrict__ bout,
    float* __restrict__ out)
{
    const int t   = blockIdx.x;
    const int tid = threadIdx.x;
    __shared__ float h2[1024];

    if (tid < 128)
        *(float4*)(h2 + tid * 4) = *(const float4*)(hsf + (size_t)t * HDIM + tid * 4);
    else
        *(float4*)(h2 + 512 + (tid - 128) * 4) = *(const float4*)(hsb + (size_t)t * HDIM + (tid - 128) * 4);
    __syncthreads();

    const int wv = tid >> 6, lane = tid & 63;
    for (int tag = wv; tag < NTAGS; tag += 4) {
        const float4* wr = (const float4*)(Wout + (size_t)tag * (2 * HDIM));
        float p = 0.0f;
        #pragma unroll
        for (int c = lane; c < 256; c += 64) {
            float4 wv4 = wr[c];
            float4 hv  = *(const float4*)(h2 + c * 4);
            p += wv4.x * hv.x + wv4.y * hv.y + wv4.z * hv.z + wv4.w * hv.w;
        }
        p += __shfl_down(p, 32, 64);
        p += __shfl_down(p, 16, 64);
        p += __shfl_down(p, 8, 64);
        p += __shfl_down(p, 4, 64);
        p += __shfl_down(p, 2, 64);
        p += __shfl_down(p, 1, 64);
        if (lane == 0) out[(size_t)t * NTAGS + tag] = p + bout[tag];
    }
}

// ---------------------------------------------------------------------------
extern "C" void kernel_launch(void* const* d_in, const int* in_sizes, int n_in,
                              void* d_out, int out_size, void* d_ws, size_t ws_size,
                              hipStream_t stream)
{
    const int*   sent  = (const int*)d_in[0];
    const float* emb   = (const float*)d_in[1];
    const float* Wih_f = (const float*)d_in[2];
    const float* Whh_f = (const float*)d_in[3];
    const float* bih_f = (const float*)d_in[4];
    const float* bhh_f = (const float*)d_in[5];
    const float* Wih_b = (const float*)d_in[6];
    const float* Whh_b = (const float*)d_in[7];
    const float* bih_b = (const float*)d_in[8];
    const float* bhh_b = (const float*)d_in[9];
    const float* Wout  = (const float*)d_in[10];
    const float* bout  = (const float*)d_in[11];
    float* out = (float*)d_out;

    char* ws = (char*)d_ws;
    // Workspace: hsf [4096*512 f32] @ 0 (8 MiB), hsb @ 8 MiB. Both double as
    // sync flags: sentinel-fill with 0xFF (-NaN, never produced by o*tanh(c)).
    float* hsf = (float*)(ws);
    float* hsb = (float*)(ws + 8388608);
    hipMemsetAsync(ws, 0xFF, 16777216, stream);

    lstm_scan<<<32, 512, 0, stream>>>(sent, emb,
                                      Wih_f, Whh_f, bih_f, bhh_f,
                                      Wih_b, Whh_b, bih_b, bhh_b,
                                      hsf, hsb);
    out_gemm<<<T_LEN, 256, 0, stream>>>(hsf, hsb, Wout, bout, out);
}

// Round 12
// 6103.688 us; speedup vs baseline: 2.0860x; 1.5538x over previous
//
#include <hip/hip_runtime.h>
#include <math.h>

#define T_LEN 4096
#define EDIM  256
#define HDIM  512
#define NTAGS 50
#define SENTW 0xFFFFFFFFu

__device__ __forceinline__ float sigm(float x) {
    return __builtin_amdgcn_rcpf(1.0f + __expf(-x));
}
__device__ __forceinline__ float tanh_fast(float x) {
    float e = __expf(2.0f * x);                       // x>>0 -> inf -> rcp=0 -> 1; x<<0 -> 0 -> -1
    return 1.0f - 2.0f * __builtin_amdgcn_rcpf(e + 1.0f);
}
__device__ __forceinline__ float u2f(unsigned u) { union { unsigned i; float f; } v; v.i = u; return v.f; }
__device__ __forceinline__ float rdlane(float v, int l) {
    union { float f; int i; } a, r;
    a.f = v;
    r.i = __builtin_amdgcn_readlane(a.i, l);   // SGPR broadcast, VALU-only
    return r.f;
}
// Agent-scope relaxed RMW poll: serviced at the device coherence point.
// Session laws (r0-r11): only coherence-point ops observe cross-CU progress;
// L2 shortcuts never work (r1/r2/r5); ring mailboxes don't cut poll RT (r7);
// same-line poll pipelining MSHR-merges (r3); tight one-word-per-lane spin
// beats every consume restructure (r6/r9); never poll before the program-
// order publish it may cover (r8); pairing independent chains is useless
// (r10); cross-wave LDS exchange is fragile (r11) - per-wave strips only.
__device__ __forceinline__ unsigned long long pollA(unsigned long long* p) {
    return __hip_atomic_fetch_or(p, 0ull, __ATOMIC_RELAXED, __HIP_MEMORY_SCOPE_AGENT);
}
__device__ __forceinline__ bool bad2(unsigned long long v) {
    return ((unsigned)v == SENTW) || ((unsigned)(v >> 32) == SENTW);
}

// ---------------------------------------------------------------------------
// Persistent bidirectional LSTM scan (f32), data-as-flag sync. Round-12 =
// round-4 byte-identical skeleton (proven 5.94 ms) with ONE change:
//   h-matvec broadcast via PER-WAVE LDS strip instead of v_readlane.
//   r4: 128 FMA + 128 readlane = 256 serial-issue instrs (~512cy) after
//   spin-exit, all on the critical path. Now: 1 ds_write_b64/lane stages the
//   wave's polled 128-col slice into its private strip (2-way bank aliasing
//   = free), then 32x UNIFORM-ADDRESS ds_read_b128 (64-lane broadcast,
//   conflict-free) + 128 FMA = ~161 instrs (~190cy saved/step). Per-wave
//   strip = intra-wave producer/consumer only: no barrier, no cross-wave
//   coupling (r9 proved this staging pattern correct; r11's failure was the
//   cross-wave variant). Parity double-buffer for WAR insurance.
// Everything else EXACT r4: 64 WGs round-robin (0..31 fwd, 32..63 bwd),
// readlane x-matvec (hidden under poll RT), pure agent fetch_or spin,
// pl[2] handoff + wave0 finalize, one 16-lane atomicExch publish.
// WG g owns hidden units [g*16,+16) => 64 gate rows. lane = row:
//   q = lane>>4 (gate i,f,g,o), u = lane&15, R = q*512 + g*16 + u.
// Wave wv owns W_hh cols [wv*128,+128), W_ih cols [wv*64,+64); lane l polls
// the 8B word covering h cols {wv*128+2l, +1}.
// ---------------------------------------------------------------------------
__global__ __launch_bounds__(256, 1) void lstm_scan(
    const int* __restrict__ sent, const float* __restrict__ emb,
    const float* __restrict__ Wih_f, const float* __restrict__ Whh_f,
    const float* __restrict__ bih_f, const float* __restrict__ bhh_f,
    const float* __restrict__ Wih_b, const float* __restrict__ Whh_b,
    const float* __restrict__ bih_b, const float* __restrict__ bhh_b,
    float* hsf, float* hsb)
{
    const int tid  = threadIdx.x;
    const int lane = tid & 63;
    const int wv   = tid >> 6;          // wave id = column block
    const int dir  = blockIdx.x >> 5;
    const int g    = blockIdx.x & 31;

    const float* Wih = dir ? Wih_b : Wih_f;
    const float* Whh = dir ? Whh_b : Whh_f;
    const float* bih = dir ? bih_b : bih_f;
    const float* bhh = dir ? bhh_b : bhh_f;
    float* hs = dir ? hsb : hsf;

    const int q = lane >> 4;
    const int u = lane & 15;
    const int R = q * 512 + g * 16 + u;

    // W_hh cols [wv*128,+128) of row R -> 128 VGPRs.
    float wh[128];
    {
        const float* base = Whh + (size_t)R * HDIM + wv * 128;
        #pragma unroll
        for (int i = 0; i < 32; ++i) {
            float4 v = *(const float4*)(base + 4 * i);
            wh[4*i] = v.x; wh[4*i+1] = v.y; wh[4*i+2] = v.z; wh[4*i+3] = v.w;
        }
    }
    // W_ih cols [wv*64,+64) of row R -> 64 VGPRs.
    float wx[64];
    {
        const float* base = Wih + (size_t)R * EDIM + wv * 64;
        #pragma unroll
        for (int i = 0; i < 16; ++i) {
            float4 v = *(const float4*)(base + 4 * i);
            wx[4*i] = v.x; wx[4*i+1] = v.y; wx[4*i+2] = v.z; wx[4*i+3] = v.w;
        }
    }
    const float bias = bih[R] + bhh[R];

    __shared__ float pl[2][256];
    // Per-wave h broadcast strip: [wave][step parity][128 floats].
    __shared__ float hst[4][2][128];

    float c_state = 0.0f;

    // Embedding value pipeline: lane holds emb[sent[t]][wv*64 + lane].
    float ecur;
    {
        int t0 = dir ? (T_LEN - 1) : 0;
        ecur = emb[(size_t)sent[t0] * EDIM + wv * 64 + lane];
    }

    for (int s = 0; s < T_LEN; ++s) {
        const int t = dir ? (T_LEN - 1 - s) : s;

        // Issue first poll sample ASAP so it flies under the x-matvec.
        unsigned long long* p = nullptr;
        unsigned long long v = 0;
        if (s > 0) {
            const int tp = dir ? (t + 1) : (t - 1);
            p = (unsigned long long*)(hs + (size_t)tp * HDIM + wv * 128) + lane;
            v = pollA(p);
        }
        // Prefetch next step's embedding value (h-independent).
        float enext = 0.0f;
        if (s + 1 < T_LEN) {
            int tn = dir ? (t - 1) : (t + 1);
            enext = emb[(size_t)sent[tn] * EDIM + wv * 64 + lane];
        }

        // x partial: 64 SGPR-broadcast MACs over 4 independent accumulators
        // (hidden under the in-flight first poll - not on the critical path).
        float a0 = 0.f, a1 = 0.f, a2 = 0.f, a3 = 0.f;
        #pragma unroll
        for (int i = 0; i < 16; ++i) {
            a0 = fmaf(wx[4*i+0], rdlane(ecur, 4*i+0), a0);
            a1 = fmaf(wx[4*i+1], rdlane(ecur, 4*i+1), a1);
            a2 = fmaf(wx[4*i+2], rdlane(ecur, 4*i+2), a2);
            a3 = fmaf(wx[4*i+3], rdlane(ecur, 4*i+3), a3);
        }

        if (s > 0) {
            // Tight single-outstanding spin (r4-proven, untouched).
            while (bad2(v)) v = pollA(p);
            // Stage this wave's polled slice into its private strip:
            // h[wv*128 + 2*lane .. +1] -> hst[wv][par][2*lane .. +1].
            // One ds_write_b64/lane; intra-wave only, no barrier needed
            // (compiler lgkmcnt orders the RAW to the reads below).
            float2 hv2 = make_float2(u2f((unsigned)v), u2f((unsigned)(v >> 32)));
            *(float2*)&hst[wv][s & 1][2 * lane] = hv2;
            // h partial: 32 uniform-address ds_read_b128 (64-lane broadcast,
            // conflict-free) + 128 FMAs over 4 chains. ~161 instrs vs r4's
            // 256 (the round's single change).
            #pragma unroll
            for (int k = 0; k < 32; ++k) {
                float4 hv = *(const float4*)&hst[wv][s & 1][4 * k];
                a0 = fmaf(wh[4*k+0], hv.x, a0);
                a1 = fmaf(wh[4*k+1], hv.y, a1);
                a2 = fmaf(wh[4*k+2], hv.z, a2);
                a3 = fmaf(wh[4*k+3], hv.w, a3);
            }
        }

        pl[s & 1][wv * 64 + lane] = (a0 + a1) + (a2 + a3);
        __syncthreads();

        // wave0 finalize (r4 structure), fast activations, one 16-lane
        // atomicExch wave-op = single 64B-line publish at the TCC.
        if (wv == 0) {
            const float* pb = pl[s & 1];
            float tot = pb[lane] + pb[64 + lane] + pb[128 + lane] + pb[192 + lane] + bias;
            float gi = __shfl(tot, u,      64);
            float gf = __shfl(tot, u + 16, 64);
            float gg = __shfl(tot, u + 32, 64);
            float go = __shfl(tot, u + 48, 64);
            if (lane < 16) {
                float iv = sigm(gi), fv = sigm(gf);
                float gv = tanh_fast(gg), ov = sigm(go);
                c_state = fv * c_state + iv * gv;
                float h = ov * tanh_fast(c_state);
                __hip_atomic_exchange(hs + (size_t)t * HDIM + g * 16 + u, h,
                                      __ATOMIC_RELAXED, __HIP_MEMORY_SCOPE_AGENT);
            }
        }
        ecur = enext;
    }
}

// ---------------------------------------------------------------------------
// tag_space[t] = [hs_f[t] | hs_b[t]] @ W_out^T + b_out  (f32 out)
// ---------------------------------------------------------------------------
__global__ __launch_bounds__(256) void out_gemm(
    const float* __restrict__ hsf, const float* __restrict__ hsb,
    const float* __restrict__ Wout, const float* __restrict__ bout,
    float* __restrict__ out)
{
    const int t   = blockIdx.x;
    const int tid = threadIdx.x;
    __shared__ float h2[1024];

    if (tid < 128)
        *(float4*)(h2 + tid * 4) = *(const float4*)(hsf + (size_t)t * HDIM + tid * 4);
    else
        *(float4*)(h2 + 512 + (tid - 128) * 4) = *(const float4*)(hsb + (size_t)t * HDIM + (tid - 128) * 4);
    __syncthreads();

    const int wv = tid >> 6, lane = tid & 63;
    for (int tag = wv; tag < NTAGS; tag += 4) {
        const float4* wr = (const float4*)(Wout + (size_t)tag * (2 * HDIM));
        float p = 0.0f;
        #pragma unroll
        for (int c = lane; c < 256; c += 64) {
            float4 wv4 = wr[c];
            float4 hv  = *(const float4*)(h2 + c * 4);
            p += wv4.x * hv.x + wv4.y * hv.y + wv4.z * hv.z + wv4.w * hv.w;
        }
        p += __shfl_down(p, 32, 64);
        p += __shfl_down(p, 16, 64);
        p += __shfl_down(p, 8, 64);
        p += __shfl_down(p, 4, 64);
        p += __shfl_down(p, 2, 64);
        p += __shfl_down(p, 1, 64);
        if (lane == 0) out[(size_t)t * NTAGS + tag] = p + bout[tag];
    }
}

// ---------------------------------------------------------------------------
extern "C" void kernel_launch(void* const* d_in, const int* in_sizes, int n_in,
                              void* d_out, int out_size, void* d_ws, size_t ws_size,
                              hipStream_t stream)
{
    const int*   sent  = (const int*)d_in[0];
    const float* emb   = (const float*)d_in[1];
    const float* Wih_f = (const float*)d_in[2];
    const float* Whh_f = (const float*)d_in[3];
    const float* bih_f = (const float*)d_in[4];
    const float* bhh_f = (const float*)d_in[5];
    const float* Wih_b = (const float*)d_in[6];
    const float* Whh_b = (const float*)d_in[7];
    const float* bih_b = (const float*)d_in[8];
    const float* bhh_b = (const float*)d_in[9];
    const float* Wout  = (const float*)d_in[10];
    const float* bout  = (const float*)d_in[11];
    float* out = (float*)d_out;

    char* ws = (char*)d_ws;
    // Workspace: hsf [4096*512 f32] @ 0 (8 MiB), hsb @ 8 MiB. Both double as
    // sync flags: sentinel-fill with 0xFF (-NaN, never produced by o*tanh(c)).
    float* hsf = (float*)(ws);
    float* hsb = (float*)(ws + 8388608);
    hipMemsetAsync(ws, 0xFF, 16777216, stream);

    lstm_scan<<<64, 256, 0, stream>>>(sent, emb,
                                      Wih_f, Whh_f, bih_f, bhh_f,
                                      Wih_b, Whh_b, bih_b, bhh_b,
                                      hsf, hsb);
    out_gemm<<<T_LEN, 256, 0, stream>>>(hsf, hsb, Wout, bout, out);
}